// Round 1
// baseline (2848.986 us; speedup 1.0000x reference)
//
#include <hip/hip_runtime.h>

#define N_NODES 50000
#define E_EDGES 800000
#define IN_F 256
#define H_F 128
#define C_OUT 10

// ---------------- degree / norm precompute ----------------

__global__ __launch_bounds__(256) void k_deg_init(float* __restrict__ deg) {
    int i = blockIdx.x * 256 + threadIdx.x;
    if (i < N_NODES) deg[i] = 1.0f;   // self loop
}

__global__ __launch_bounds__(256) void k_deg_count(const int* __restrict__ dst,
                                                   float* __restrict__ deg) {
    int e = blockIdx.x * 256 + threadIdx.x;
    if (e < E_EDGES) unsafeAtomicAdd(&deg[dst[e]], 1.0f);
}

__global__ __launch_bounds__(256) void k_dinv(const float* __restrict__ deg,
                                              float* __restrict__ dinv) {
    int i = blockIdx.x * 256 + threadIdx.x;
    if (i < N_NODES) dinv[i] = 1.0f / sqrtf(deg[i]);
}

__global__ __launch_bounds__(256) void k_wedge(const int* __restrict__ src,
                                               const int* __restrict__ dst,
                                               const float* __restrict__ dinv,
                                               float* __restrict__ w) {
    int e = blockIdx.x * 256 + threadIdx.x;
    if (e < E_EDGES) w[e] = dinv[src[e]] * dinv[dst[e]];
}

// ---------------- aggregation ----------------

// agg[i] = hW[i] * dinv[i]^2   (self-loop contribution; also initializes agg)
__global__ __launch_bounds__(256) void k_self(const float* __restrict__ hW,
                                              const float* __restrict__ dinv,
                                              float* __restrict__ agg) {
    int id = blockIdx.x * 256 + threadIdx.x;   // N*32 items, float4 each
    int i = id >> 5, g = id & 31;
    if (i >= N_NODES) return;
    float s = dinv[i]; s = s * s;
    float4 v = *(const float4*)(hW + (size_t)i * H_F + g * 4);
    v.x *= s; v.y *= s; v.z *= s; v.w *= s;
    *(float4*)(agg + (size_t)i * H_F + g * 4) = v;
}

// agg[dst[e]] += hW[src[e]] * w[e]   (32 lanes/edge, float4/lane)
__global__ __launch_bounds__(256) void k_scatter(const int* __restrict__ src,
                                                 const int* __restrict__ dst,
                                                 const float* __restrict__ w,
                                                 const float* __restrict__ hW,
                                                 float* __restrict__ agg) {
    long long id = (long long)blockIdx.x * 256 + threadIdx.x;  // E*32 items
    int e = (int)(id >> 5);
    int g = (int)(id & 31);
    if (e >= E_EDGES) return;
    int s = src[e], d = dst[e];
    float we = w[e];
    float4 v = *(const float4*)(hW + (size_t)s * H_F + g * 4);
    float* out = agg + (size_t)d * H_F + g * 4;
    unsafeAtomicAdd(out + 0, v.x * we);
    unsafeAtomicAdd(out + 1, v.y * we);
    unsafeAtomicAdd(out + 2, v.z * we);
    unsafeAtomicAdd(out + 3, v.w * we);
}

// h[i] = relu(agg[i]/deg[i] + bias)
__global__ __launch_bounds__(256) void k_post(const float* __restrict__ agg,
                                              const float* __restrict__ deg,
                                              const float* __restrict__ bias,
                                              float* __restrict__ h) {
    int id = blockIdx.x * 256 + threadIdx.x;   // N*32
    int i = id >> 5, g = id & 31;
    if (i >= N_NODES) return;
    float rd = 1.0f / deg[i];
    float4 v = *(const float4*)(agg + (size_t)i * H_F + g * 4);
    float4 b = *(const float4*)(bias + g * 4);
    v.x = fmaxf(fmaf(v.x, rd, b.x), 0.0f);
    v.y = fmaxf(fmaf(v.y, rd, b.y), 0.0f);
    v.z = fmaxf(fmaf(v.z, rd, b.z), 0.0f);
    v.w = fmaxf(fmaf(v.w, rd, b.w), 0.0f);
    *(float4*)(h + (size_t)i * H_F + g * 4) = v;
}

// ---------------- fp32 GEMM: C[M x 128] = A[M x K] @ B[K x 128] ----------------
// 128x128 tile per 256-thread block, BK=16, 8x8 per thread.

template <int K>
__global__ __launch_bounds__(256) void k_gemm(const float* __restrict__ A,
                                              const float* __restrict__ B,
                                              float* __restrict__ C) {
    __shared__ float As[16][132];
    __shared__ float Bs[16][132];
    const int tid = threadIdx.x;
    const int brow = blockIdx.x * 128;
    const int tr = (tid >> 4) * 8;
    const int tc = (tid & 15) * 8;
    const int arow = tid >> 2;         // 0..63
    const int akk  = (tid & 3) * 4;    // 0..12
    const int bkr  = tid >> 5;         // 0..7
    const int bcc  = (tid & 31) * 4;   // 0..124

    float acc[8][8] = {};

    for (int kt = 0; kt < K; kt += 16) {
#pragma unroll
        for (int half = 0; half < 2; ++half) {
            int m = arow + half * 64;
            int gr = brow + m;
            float4 v = make_float4(0.f, 0.f, 0.f, 0.f);
            if (gr < N_NODES) v = *(const float4*)(A + (size_t)gr * K + kt + akk);
            As[akk + 0][m] = v.x;
            As[akk + 1][m] = v.y;
            As[akk + 2][m] = v.z;
            As[akk + 3][m] = v.w;
        }
#pragma unroll
        for (int half = 0; half < 2; ++half) {
            int k = bkr + half * 8;
            *(float4*)&Bs[k][bcc] = *(const float4*)(B + (size_t)(kt + k) * H_F + bcc);
        }
        __syncthreads();
#pragma unroll
        for (int k = 0; k < 16; ++k) {
            float4 a0 = *(const float4*)&As[k][tr];
            float4 a1 = *(const float4*)&As[k][tr + 4];
            float4 b0 = *(const float4*)&Bs[k][tc];
            float4 b1 = *(const float4*)&Bs[k][tc + 4];
            float a[8] = {a0.x, a0.y, a0.z, a0.w, a1.x, a1.y, a1.z, a1.w};
            float b[8] = {b0.x, b0.y, b0.z, b0.w, b1.x, b1.y, b1.z, b1.w};
#pragma unroll
            for (int i = 0; i < 8; ++i)
#pragma unroll
                for (int j = 0; j < 8; ++j)
                    acc[i][j] = fmaf(a[i], b[j], acc[i][j]);
        }
        __syncthreads();
    }
#pragma unroll
    for (int i = 0; i < 8; ++i) {
        int gr = brow + tr + i;
        if (gr < N_NODES) {
            float4 c0 = {acc[i][0], acc[i][1], acc[i][2], acc[i][3]};
            float4 c1 = {acc[i][4], acc[i][5], acc[i][6], acc[i][7]};
            *(float4*)(C + (size_t)gr * H_F + tc) = c0;
            *(float4*)(C + (size_t)gr * H_F + tc + 4) = c1;
        }
    }
}

// ---------------- final projection: out[N x 10] = H @ Wc + bc ----------------

__global__ __launch_bounds__(256) void k_out(const float* __restrict__ Hf,
                                             const float* __restrict__ Wc,
                                             const float* __restrict__ bc,
                                             float* __restrict__ out) {
    int id = blockIdx.x * 256 + threadIdx.x;
    if (id >= N_NODES * C_OUT) return;
    int row = id / C_OUT;
    int col = id - row * C_OUT;
    const float4* h4 = (const float4*)(Hf + (size_t)row * H_F);
    float sum = bc[col];
#pragma unroll
    for (int k4 = 0; k4 < 32; ++k4) {
        float4 v = h4[k4];
        sum = fmaf(v.x, Wc[(k4 * 4 + 0) * C_OUT + col], sum);
        sum = fmaf(v.y, Wc[(k4 * 4 + 1) * C_OUT + col], sum);
        sum = fmaf(v.z, Wc[(k4 * 4 + 2) * C_OUT + col], sum);
        sum = fmaf(v.w, Wc[(k4 * 4 + 3) * C_OUT + col], sum);
    }
    out[id] = sum;
}

// ---------------- launch ----------------

extern "C" void kernel_launch(void* const* d_in, const int* in_sizes, int n_in,
                              void* d_out, int out_size, void* d_ws, size_t ws_size,
                              hipStream_t stream) {
    const float* x  = (const float*)d_in[0];
    const int*   ei = (const int*)d_in[1];
    const float* W1 = (const float*)d_in[2];
    const float* b1 = (const float*)d_in[3];
    const float* W2 = (const float*)d_in[4];
    const float* b2 = (const float*)d_in[5];
    const float* Wc = (const float*)d_in[6];
    const float* bc = (const float*)d_in[7];
    const int* esrc = ei;
    const int* edst = ei + E_EDGES;

    float* ws   = (float*)d_ws;
    float* deg  = ws;
    float* dinv = deg + N_NODES;
    float* wE   = dinv + N_NODES;
    float* bufA = wE + E_EDGES;                   // hW  (N x 128)
    float* bufB = bufA + (size_t)N_NODES * H_F;   // agg (N x 128)
    float* bufC = bufB + (size_t)N_NODES * H_F;   // h   (N x 128)
    float* out  = (float*)d_out;

    const int gN   = (N_NODES + 255) / 256;
    const int gE   = (E_EDGES + 255) / 256;
    const int gN32 = (N_NODES * 32 + 255) / 256;
    const int gE32 = (int)(((long long)E_EDGES * 32 + 255) / 256);
    const int gGemm = (N_NODES + 127) / 128;

    k_deg_init<<<gN, 256, 0, stream>>>(deg);
    k_deg_count<<<gE, 256, 0, stream>>>(edst, deg);
    k_dinv<<<gN, 256, 0, stream>>>(deg, dinv);
    k_wedge<<<gE, 256, 0, stream>>>(esrc, edst, dinv, wE);

    // layer 1
    k_gemm<IN_F><<<gGemm, 256, 0, stream>>>(x, W1, bufA);
    k_self<<<gN32, 256, 0, stream>>>(bufA, dinv, bufB);
    k_scatter<<<gE32, 256, 0, stream>>>(esrc, edst, wE, bufA, bufB);
    k_post<<<gN32, 256, 0, stream>>>(bufB, deg, b1, bufC);

    // layer 2
    k_gemm<H_F><<<gGemm, 256, 0, stream>>>(bufC, W2, bufA);
    k_self<<<gN32, 256, 0, stream>>>(bufA, dinv, bufB);
    k_scatter<<<gE32, 256, 0, stream>>>(esrc, edst, wE, bufA, bufB);
    k_post<<<gN32, 256, 0, stream>>>(bufB, deg, b2, bufC);

    // classifier
    k_out<<<(N_NODES * C_OUT + 255) / 256, 256, 0, stream>>>(bufC, Wc, bc, out);
}

// Round 2
// 343.063 us; speedup vs baseline: 8.3046x; 8.3046x over previous
//
#include <hip/hip_runtime.h>

#define N_NODES 50000
#define E_EDGES 800000
#define IN_F 256
#define H_F 128
#define C_OUT 10
#define NB_SCAN ((N_NODES + 255) / 256)   // 196, must be <= 256
static_assert(NB_SCAN <= 256, "scan2 assumes <=256 partials");

// ---------------- CSR build: count, scan, bucket ----------------

__global__ __launch_bounds__(256) void k_zero_cnt(int* __restrict__ cnt) {
    int i = blockIdx.x * 256 + threadIdx.x;
    if (i < N_NODES) cnt[i] = 0;
}

__global__ __launch_bounds__(256) void k_count(const int* __restrict__ dst,
                                               int* __restrict__ cnt) {
    int e = blockIdx.x * 256 + threadIdx.x;
    if (e < E_EDGES) atomicAdd(&cnt[dst[e]], 1);
}

// per-block exclusive scan; block totals to part[]
__global__ __launch_bounds__(256) void k_scan1(const int* __restrict__ cnt,
                                               int* __restrict__ row_off,
                                               int* __restrict__ part) {
    __shared__ int sm[256];
    int tid = threadIdx.x;
    int i = blockIdx.x * 256 + tid;
    int v = (i < N_NODES) ? cnt[i] : 0;
    sm[tid] = v;
    __syncthreads();
#pragma unroll
    for (int off = 1; off < 256; off <<= 1) {
        int t = (tid >= off) ? sm[tid - off] : 0;
        __syncthreads();
        sm[tid] += t;
        __syncthreads();
    }
    if (i < N_NODES) row_off[i] = sm[tid] - v;   // exclusive
    if (tid == 255) part[blockIdx.x] = sm[255];  // block total
}

// exclusive scan of the block totals (single block)
__global__ __launch_bounds__(256) void k_scan2(int* __restrict__ part) {
    __shared__ int sm[256];
    int tid = threadIdx.x;
    int v = (tid < NB_SCAN) ? part[tid] : 0;
    sm[tid] = v;
    __syncthreads();
#pragma unroll
    for (int off = 1; off < 256; off <<= 1) {
        int t = (tid >= off) ? sm[tid - off] : 0;
        __syncthreads();
        sm[tid] += t;
        __syncthreads();
    }
    if (tid < NB_SCAN) part[tid] = sm[tid] - v;  // exclusive
}

// add block offsets; init cursor; dinv = rsqrt(deg) with deg = cnt+1 (self loop)
__global__ __launch_bounds__(256) void k_scan3(const int* __restrict__ cnt,
                                               const int* __restrict__ part,
                                               int* __restrict__ row_off,
                                               int* __restrict__ cursor,
                                               float* __restrict__ dinv) {
    int i = blockIdx.x * 256 + threadIdx.x;
    if (i >= N_NODES) return;
    int ro = row_off[i] + part[blockIdx.x];
    row_off[i] = ro;
    cursor[i] = ro;
    dinv[i] = rsqrtf((float)(cnt[i] + 1));
}

// permute edges into CSR slots; store src index and sym-norm weight
__global__ __launch_bounds__(256) void k_bucket(const int* __restrict__ src,
                                                const int* __restrict__ dst,
                                                const float* __restrict__ dinv,
                                                int* __restrict__ cursor,
                                                int* __restrict__ csr_src,
                                                float* __restrict__ csr_w) {
    int e = blockIdx.x * 256 + threadIdx.x;
    if (e >= E_EDGES) return;
    int s = src[e], d = dst[e];
    int pos = atomicAdd(&cursor[d], 1);
    csr_src[pos] = s;
    csr_w[pos] = dinv[s] * dinv[d];
}

// ---------------- fused aggregate + mean + bias + relu ----------------
// one wave per node; lane covers float2 at feature 2*lane

__global__ __launch_bounds__(256) void k_agg(const float* __restrict__ hW,
                                             const int* __restrict__ row_off,
                                             const int* __restrict__ cnt,
                                             const int* __restrict__ csr_src,
                                             const float* __restrict__ csr_w,
                                             const float* __restrict__ dinv,
                                             const float* __restrict__ bias,
                                             float* __restrict__ h) {
    int node = blockIdx.x * 4 + (threadIdx.x >> 6);
    int lane = threadIdx.x & 63;
    if (node >= N_NODES) return;
    const float2* hw2 = (const float2*)hW;
    float2 bv = ((const float2*)bias)[lane];
    float iv = dinv[node];
    float2 acc = hw2[(size_t)node * 64 + lane];
    float s2 = iv * iv;
    acc.x *= s2; acc.y *= s2;                      // self-loop term
    int beg = row_off[node];
    int c = cnt[node];
    int j = 0;
    for (; j + 2 <= c; j += 2) {                   // 2 edges in flight
        int   s0 = csr_src[beg + j],     s1 = csr_src[beg + j + 1];
        float w0 = csr_w[beg + j],       w1 = csr_w[beg + j + 1];
        float2 v0 = hw2[(size_t)s0 * 64 + lane];
        float2 v1 = hw2[(size_t)s1 * 64 + lane];
        acc.x = fmaf(w1, v1.x, fmaf(w0, v0.x, acc.x));
        acc.y = fmaf(w1, v1.y, fmaf(w0, v0.y, acc.y));
    }
    if (j < c) {
        int   s0 = csr_src[beg + j];
        float w0 = csr_w[beg + j];
        float2 v0 = hw2[(size_t)s0 * 64 + lane];
        acc.x = fmaf(w0, v0.x, acc.x);
        acc.y = fmaf(w0, v0.y, acc.y);
    }
    float rd = 1.0f / (float)(c + 1);              // mean over deg (incl. self)
    float2 o;
    o.x = fmaxf(fmaf(acc.x, rd, bv.x), 0.0f);
    o.y = fmaxf(fmaf(acc.y, rd, bv.y), 0.0f);
    ((float2*)h)[(size_t)node * 64 + lane] = o;
}

// ---------------- fp32 GEMM: C[M x 128] = A[M x K] @ B[K x 128] ----------------

template <int K>
__global__ __launch_bounds__(256) void k_gemm(const float* __restrict__ A,
                                              const float* __restrict__ B,
                                              float* __restrict__ C) {
    __shared__ float As[16][132];
    __shared__ float Bs[16][132];
    const int tid = threadIdx.x;
    const int brow = blockIdx.x * 128;
    const int tr = (tid >> 4) * 8;
    const int tc = (tid & 15) * 8;
    const int arow = tid >> 2;         // 0..63
    const int akk  = (tid & 3) * 4;    // 0..12
    const int bkr  = tid >> 5;         // 0..7
    const int bcc  = (tid & 31) * 4;   // 0..124

    float acc[8][8] = {};

    for (int kt = 0; kt < K; kt += 16) {
#pragma unroll
        for (int half = 0; half < 2; ++half) {
            int m = arow + half * 64;
            int gr = brow + m;
            float4 v = make_float4(0.f, 0.f, 0.f, 0.f);
            if (gr < N_NODES) v = *(const float4*)(A + (size_t)gr * K + kt + akk);
            As[akk + 0][m] = v.x;
            As[akk + 1][m] = v.y;
            As[akk + 2][m] = v.z;
            As[akk + 3][m] = v.w;
        }
#pragma unroll
        for (int half = 0; half < 2; ++half) {
            int k = bkr + half * 8;
            *(float4*)&Bs[k][bcc] = *(const float4*)(B + (size_t)(kt + k) * H_F + bcc);
        }
        __syncthreads();
#pragma unroll
        for (int k = 0; k < 16; ++k) {
            float4 a0 = *(const float4*)&As[k][tr];
            float4 a1 = *(const float4*)&As[k][tr + 4];
            float4 b0 = *(const float4*)&Bs[k][tc];
            float4 b1 = *(const float4*)&Bs[k][tc + 4];
            float a[8] = {a0.x, a0.y, a0.z, a0.w, a1.x, a1.y, a1.z, a1.w};
            float b[8] = {b0.x, b0.y, b0.z, b0.w, b1.x, b1.y, b1.z, b1.w};
#pragma unroll
            for (int i = 0; i < 8; ++i)
#pragma unroll
                for (int j = 0; j < 8; ++j)
                    acc[i][j] = fmaf(a[i], b[j], acc[i][j]);
        }
        __syncthreads();
    }
#pragma unroll
    for (int i = 0; i < 8; ++i) {
        int gr = brow + tr + i;
        if (gr < N_NODES) {
            float4 c0 = {acc[i][0], acc[i][1], acc[i][2], acc[i][3]};
            float4 c1 = {acc[i][4], acc[i][5], acc[i][6], acc[i][7]};
            *(float4*)(C + (size_t)gr * H_F + tc) = c0;
            *(float4*)(C + (size_t)gr * H_F + tc + 4) = c1;
        }
    }
}

// ---------------- final projection: out[N x 10] = H @ Wc + bc ----------------

__global__ __launch_bounds__(256) void k_out(const float* __restrict__ Hf,
                                             const float* __restrict__ Wc,
                                             const float* __restrict__ bc,
                                             float* __restrict__ out) {
    int id = blockIdx.x * 256 + threadIdx.x;
    if (id >= N_NODES * C_OUT) return;
    int row = id / C_OUT;
    int col = id - row * C_OUT;
    const float4* h4 = (const float4*)(Hf + (size_t)row * H_F);
    float sum = bc[col];
#pragma unroll
    for (int k4 = 0; k4 < 32; ++k4) {
        float4 v = h4[k4];
        sum = fmaf(v.x, Wc[(k4 * 4 + 0) * C_OUT + col], sum);
        sum = fmaf(v.y, Wc[(k4 * 4 + 1) * C_OUT + col], sum);
        sum = fmaf(v.z, Wc[(k4 * 4 + 2) * C_OUT + col], sum);
        sum = fmaf(v.w, Wc[(k4 * 4 + 3) * C_OUT + col], sum);
    }
    out[id] = sum;
}

// ---------------- launch ----------------

extern "C" void kernel_launch(void* const* d_in, const int* in_sizes, int n_in,
                              void* d_out, int out_size, void* d_ws, size_t ws_size,
                              hipStream_t stream) {
    const float* x  = (const float*)d_in[0];
    const int*   ei = (const int*)d_in[1];
    const float* W1 = (const float*)d_in[2];
    const float* b1 = (const float*)d_in[3];
    const float* W2 = (const float*)d_in[4];
    const float* b2 = (const float*)d_in[5];
    const float* Wc = (const float*)d_in[6];
    const float* bc = (const float*)d_in[7];
    const int* esrc = ei;
    const int* edst = ei + E_EDGES;

    char* ws = (char*)d_ws;
    int*   cnt     = (int*)ws;                    ws += sizeof(int) * N_NODES;
    int*   row_off = (int*)ws;                    ws += sizeof(int) * N_NODES;
    int*   cursor  = (int*)ws;                    ws += sizeof(int) * N_NODES;
    float* dinv    = (float*)ws;                  ws += sizeof(float) * N_NODES;
    int*   part    = (int*)ws;                    ws += sizeof(int) * 256;
    int*   csr_src = (int*)ws;                    ws += sizeof(int) * E_EDGES;
    float* csr_w   = (float*)ws;                  ws += sizeof(float) * E_EDGES;
    float* bufA    = (float*)ws;                  ws += sizeof(float) * (size_t)N_NODES * H_F;
    float* bufC    = (float*)ws;
    float* out = (float*)d_out;

    const int gN = (N_NODES + 255) / 256;
    const int gE = (E_EDGES + 255) / 256;
    const int gAgg = (N_NODES + 3) / 4;
    const int gGemm = (N_NODES + 127) / 128;

    // CSR build (graph fixed per call; rebuilt every call for determinism)
    k_zero_cnt<<<gN, 256, 0, stream>>>(cnt);
    k_count<<<gE, 256, 0, stream>>>(edst, cnt);
    k_scan1<<<NB_SCAN, 256, 0, stream>>>(cnt, row_off, part);
    k_scan2<<<1, 256, 0, stream>>>(part);
    k_scan3<<<NB_SCAN, 256, 0, stream>>>(cnt, part, row_off, cursor, dinv);
    k_bucket<<<gE, 256, 0, stream>>>(esrc, edst, dinv, cursor, csr_src, csr_w);

    // layer 1
    k_gemm<IN_F><<<gGemm, 256, 0, stream>>>(x, W1, bufA);
    k_agg<<<gAgg, 256, 0, stream>>>(bufA, row_off, cnt, csr_src, csr_w, dinv, b1, bufC);

    // layer 2
    k_gemm<H_F><<<gGemm, 256, 0, stream>>>(bufC, W2, bufA);
    k_agg<<<gAgg, 256, 0, stream>>>(bufA, row_off, cnt, csr_src, csr_w, dinv, b2, bufC);

    // classifier
    k_out<<<(N_NODES * C_OUT + 255) / 256, 256, 0, stream>>>(bufC, Wc, bc, out);
}

// Round 3
// 289.625 us; speedup vs baseline: 9.8368x; 1.1845x over previous
//
#include <hip/hip_runtime.h>

#define N_NODES 50000
#define E_EDGES 800000
#define IN_F 256
#define H_F 128
#define C_OUT 10
#define NB_SCAN ((N_NODES + 255) / 256)   // 196, must be <= 256
static_assert(NB_SCAN <= 256, "scan2 assumes <=256 partials");

// ---------------- CSR build: count, scan, bucket ----------------

__global__ __launch_bounds__(256) void k_zero_cnt(int* __restrict__ cnt) {
    int i = blockIdx.x * 256 + threadIdx.x;
    if (i < N_NODES) cnt[i] = 0;
}

__global__ __launch_bounds__(256) void k_count(const int* __restrict__ dst,
                                               int* __restrict__ cnt) {
    int e = blockIdx.x * 256 + threadIdx.x;
    if (e < E_EDGES) atomicAdd(&cnt[dst[e]], 1);
}

__global__ __launch_bounds__(256) void k_scan1(const int* __restrict__ cnt,
                                               int* __restrict__ row_off,
                                               int* __restrict__ part) {
    __shared__ int sm[256];
    int tid = threadIdx.x;
    int i = blockIdx.x * 256 + tid;
    int v = (i < N_NODES) ? cnt[i] : 0;
    sm[tid] = v;
    __syncthreads();
#pragma unroll
    for (int off = 1; off < 256; off <<= 1) {
        int t = (tid >= off) ? sm[tid - off] : 0;
        __syncthreads();
        sm[tid] += t;
        __syncthreads();
    }
    if (i < N_NODES) row_off[i] = sm[tid] - v;   // exclusive
    if (tid == 255) part[blockIdx.x] = sm[255];  // block total
}

__global__ __launch_bounds__(256) void k_scan2(int* __restrict__ part) {
    __shared__ int sm[256];
    int tid = threadIdx.x;
    int v = (tid < NB_SCAN) ? part[tid] : 0;
    sm[tid] = v;
    __syncthreads();
#pragma unroll
    for (int off = 1; off < 256; off <<= 1) {
        int t = (tid >= off) ? sm[tid - off] : 0;
        __syncthreads();
        sm[tid] += t;
        __syncthreads();
    }
    if (tid < NB_SCAN) part[tid] = sm[tid] - v;  // exclusive
}

__global__ __launch_bounds__(256) void k_scan3(const int* __restrict__ cnt,
                                               const int* __restrict__ part,
                                               int* __restrict__ row_off,
                                               int* __restrict__ cursor,
                                               float* __restrict__ dinv) {
    int i = blockIdx.x * 256 + threadIdx.x;
    if (i >= N_NODES) return;
    int ro = row_off[i] + part[blockIdx.x];
    row_off[i] = ro;
    cursor[i] = ro;
    dinv[i] = rsqrtf((float)(cnt[i] + 1));
}

// permute edges into CSR slots; pack (src, weight) into one int2
__global__ __launch_bounds__(256) void k_bucket(const int* __restrict__ src,
                                                const int* __restrict__ dst,
                                                const float* __restrict__ dinv,
                                                int* __restrict__ cursor,
                                                int2* __restrict__ csr) {
    int e = blockIdx.x * 256 + threadIdx.x;
    if (e >= E_EDGES) return;
    int s = src[e], d = dst[e];
    int pos = atomicAdd(&cursor[d], 1);
    csr[pos] = make_int2(s, __float_as_int(dinv[s] * dinv[d]));
}

// ---------------- fused aggregate + mean + bias + relu (+ classifier) ----------------
// one wave per node; lane covers float2 at feature 2*lane

template <bool FUSE_OUT>
__global__ __launch_bounds__(256) void k_agg(const float* __restrict__ hW,
                                             const int* __restrict__ row_off,
                                             const int* __restrict__ cnt,
                                             const int2* __restrict__ csr,
                                             const float* __restrict__ dinv,
                                             const float* __restrict__ bias,
                                             const float* __restrict__ Wc,
                                             const float* __restrict__ bc,
                                             float* __restrict__ outp) {
    int node = blockIdx.x * 4 + (threadIdx.x >> 6);
    int lane = threadIdx.x & 63;
    if (node >= N_NODES) return;
    const float2* hw2 = (const float2*)hW;
    float iv = dinv[node];
    float2 acc = hw2[(size_t)node * 64 + lane];
    float s2 = iv * iv;
    acc.x *= s2; acc.y *= s2;                      // self-loop term
    int beg = row_off[node];
    int c = cnt[node];
    int j = 0;
    for (; j + 4 <= c; j += 4) {
        int2 e0 = csr[beg + j],     e1 = csr[beg + j + 1];
        int2 e2 = csr[beg + j + 2], e3 = csr[beg + j + 3];
        float2 v0 = hw2[(size_t)e0.x * 64 + lane];
        float2 v1 = hw2[(size_t)e1.x * 64 + lane];
        float2 v2 = hw2[(size_t)e2.x * 64 + lane];
        float2 v3 = hw2[(size_t)e3.x * 64 + lane];
        float w0 = __int_as_float(e0.y), w1 = __int_as_float(e1.y);
        float w2 = __int_as_float(e2.y), w3 = __int_as_float(e3.y);
        acc.x = fmaf(w0, v0.x, acc.x); acc.y = fmaf(w0, v0.y, acc.y);
        acc.x = fmaf(w1, v1.x, acc.x); acc.y = fmaf(w1, v1.y, acc.y);
        acc.x = fmaf(w2, v2.x, acc.x); acc.y = fmaf(w2, v2.y, acc.y);
        acc.x = fmaf(w3, v3.x, acc.x); acc.y = fmaf(w3, v3.y, acc.y);
    }
    for (; j < c; ++j) {
        int2 e0 = csr[beg + j];
        float w0 = __int_as_float(e0.y);
        float2 v0 = hw2[(size_t)e0.x * 64 + lane];
        acc.x = fmaf(w0, v0.x, acc.x);
        acc.y = fmaf(w0, v0.y, acc.y);
    }
    float rd = 1.0f / (float)(c + 1);              // mean over deg (incl. self)
    float2 bv = ((const float2*)bias)[lane];
    float2 o;
    o.x = fmaxf(fmaf(acc.x, rd, bv.x), 0.0f);
    o.y = fmaxf(fmaf(acc.y, rd, bv.y), 0.0f);
    if (!FUSE_OUT) {
        ((float2*)outp)[(size_t)node * 64 + lane] = o;
    } else {
        // out[node][c] = sum_f h[f]*Wc[f][c] + bc[c]; lane owns feats 2l, 2l+1
        float po[C_OUT];
#pragma unroll
        for (int cc = 0; cc < C_OUT; ++cc)
            po[cc] = fmaf(o.x, Wc[(2 * lane) * C_OUT + cc],
                          o.y * Wc[(2 * lane + 1) * C_OUT + cc]);
#pragma unroll
        for (int off = 32; off; off >>= 1)
#pragma unroll
            for (int cc = 0; cc < C_OUT; ++cc)
                po[cc] += __shfl_xor(po[cc], off, 64);
        if (lane == 0) {
#pragma unroll
            for (int cc = 0; cc < C_OUT; ++cc)
                outp[(size_t)node * C_OUT + cc] = po[cc] + bc[cc];
        }
    }
}

// ---------------- fp32 GEMM: C[M x 128] = A[M x K] @ B[K x 128] ----------------
// 64x128 tile per 256-thread block, BK=32, 4x8 per thread.

template <int K>
__global__ __launch_bounds__(256, 4) void k_gemm(const float* __restrict__ A,
                                                 const float* __restrict__ B,
                                                 float* __restrict__ C) {
    __shared__ float As[32][68];    // [k][m], pad 68 for b128-aligned reads
    __shared__ float Bs[32][132];   // [k][n]
    const int tid = threadIdx.x;
    const int brow = blockIdx.x * 64;
    const int tr4 = (tid >> 4) * 4;       // 4 rows
    const int tc4 = (tid & 15) * 4;       // 4+4 cols (tc4, tc4+64)
    const int ar  = tid >> 2;             // 0..63 (A row)
    const int akk = (tid & 3) * 4;        // k chunks {akk, akk+16}
    const int bqr = tid >> 5;             // 0..7
    const int bqc = (tid & 31) * 4;       // 0..124

    float acc[4][8] = {};
    const int arow_g = brow + ar;
    const bool arow_ok = arow_g < N_NODES;
    const float* Arow = A + (size_t)arow_g * K;

    for (int kt = 0; kt < K; kt += 32) {
        float4 va0 = make_float4(0.f, 0.f, 0.f, 0.f), va1 = va0;
        if (arow_ok) {
            va0 = *(const float4*)(Arow + kt + akk);
            va1 = *(const float4*)(Arow + kt + akk + 16);
        }
        As[akk + 0][ar] = va0.x;  As[akk + 1][ar] = va0.y;
        As[akk + 2][ar] = va0.z;  As[akk + 3][ar] = va0.w;
        As[akk + 16][ar] = va1.x; As[akk + 17][ar] = va1.y;
        As[akk + 18][ar] = va1.z; As[akk + 19][ar] = va1.w;
#pragma unroll
        for (int q = 0; q < 4; ++q) {
            int r = q * 8 + bqr;
            *(float4*)&Bs[r][bqc] = *(const float4*)(B + (size_t)(kt + r) * H_F + bqc);
        }
        __syncthreads();
#pragma unroll
        for (int k = 0; k < 32; ++k) {
            float4 a4 = *(const float4*)&As[k][tr4];
            float4 b0 = *(const float4*)&Bs[k][tc4];
            float4 b1 = *(const float4*)&Bs[k][tc4 + 64];
            float av[4] = {a4.x, a4.y, a4.z, a4.w};
            float bv[8] = {b0.x, b0.y, b0.z, b0.w, b1.x, b1.y, b1.z, b1.w};
#pragma unroll
            for (int i = 0; i < 4; ++i)
#pragma unroll
                for (int jj = 0; jj < 8; ++jj)
                    acc[i][jj] = fmaf(av[i], bv[jj], acc[i][jj]);
        }
        __syncthreads();
    }
#pragma unroll
    for (int i = 0; i < 4; ++i) {
        int gr = brow + tr4 + i;
        if (gr < N_NODES) {
            float4 c0 = {acc[i][0], acc[i][1], acc[i][2], acc[i][3]};
            float4 c1 = {acc[i][4], acc[i][5], acc[i][6], acc[i][7]};
            *(float4*)(C + (size_t)gr * H_F + tc4) = c0;
            *(float4*)(C + (size_t)gr * H_F + tc4 + 64) = c1;
        }
    }
}

// ---------------- launch ----------------

extern "C" void kernel_launch(void* const* d_in, const int* in_sizes, int n_in,
                              void* d_out, int out_size, void* d_ws, size_t ws_size,
                              hipStream_t stream) {
    const float* x  = (const float*)d_in[0];
    const int*   ei = (const int*)d_in[1];
    const float* W1 = (const float*)d_in[2];
    const float* b1 = (const float*)d_in[3];
    const float* W2 = (const float*)d_in[4];
    const float* b2 = (const float*)d_in[5];
    const float* Wc = (const float*)d_in[6];
    const float* bc = (const float*)d_in[7];
    const int* esrc = ei;
    const int* edst = ei + E_EDGES;

    char* ws = (char*)d_ws;
    int*   cnt     = (int*)ws;                    ws += sizeof(int) * N_NODES;
    int*   row_off = (int*)ws;                    ws += sizeof(int) * N_NODES;
    int*   cursor  = (int*)ws;                    ws += sizeof(int) * N_NODES;
    float* dinv    = (float*)ws;                  ws += sizeof(float) * N_NODES;
    int*   part    = (int*)ws;                    ws += sizeof(int) * 256;
    ws = (char*)(((size_t)ws + 15) & ~(size_t)15);
    int2*  csr     = (int2*)ws;                   ws += sizeof(int2) * E_EDGES;
    float* bufA    = (float*)ws;                  ws += sizeof(float) * (size_t)N_NODES * H_F;
    float* bufC    = (float*)ws;
    float* out = (float*)d_out;

    const int gN = (N_NODES + 255) / 256;
    const int gE = (E_EDGES + 255) / 256;
    const int gAgg = (N_NODES + 3) / 4;
    const int gGemm = (N_NODES + 63) / 64;

    // CSR build (graph fixed per call; rebuilt every call for determinism)
    k_zero_cnt<<<gN, 256, 0, stream>>>(cnt);
    k_count<<<gE, 256, 0, stream>>>(edst, cnt);
    k_scan1<<<NB_SCAN, 256, 0, stream>>>(cnt, row_off, part);
    k_scan2<<<1, 256, 0, stream>>>(part);
    k_scan3<<<NB_SCAN, 256, 0, stream>>>(cnt, part, row_off, cursor, dinv);
    k_bucket<<<gE, 256, 0, stream>>>(esrc, edst, dinv, cursor, csr);

    // layer 1
    k_gemm<IN_F><<<gGemm, 256, 0, stream>>>(x, W1, bufA);
    k_agg<false><<<gAgg, 256, 0, stream>>>(bufA, row_off, cnt, csr, dinv, b1,
                                           nullptr, nullptr, bufC);

    // layer 2 (+ fused classifier)
    k_gemm<H_F><<<gGemm, 256, 0, stream>>>(bufC, W2, bufA);
    k_agg<true><<<gAgg, 256, 0, stream>>>(bufA, row_off, cnt, csr, dinv, b2,
                                          Wc, bc, out);
}